// Round 3
// baseline (658.250 us; speedup 1.0000x reference)
//
#include <hip/hip_runtime.h>
#include <hip/hip_bf16.h>

// ---- problem constants (from reference) ----
#define NB 2
#define NT 3
#define NCAM 6
#define NC 16
#define FD 48
#define FH 24
#define FW 64
#define GX 100
#define GY 100
#define GZ 8
#define OC 40
#define NVOX (GX * GY * GZ)          // 80000
#define FSZ (FD * FH * FW)           // 73728 voxels per channel volume
#define CAMSZ (NC * FSZ)             // per-camera feature volume (orig layout)
#define BTSZ (NCAM * CAMSZ)          // per-(b,t) feature block (orig layout)
#define HSZ ((size_t)NB * NT * OC * NVOX)             // 19,200,000 elems
#define FT_ELEMS ((size_t)NB * NT * NCAM * FSZ * NC)  // 42,467,328 elems

static __device__ __forceinline__ unsigned short f2bf_rne(float x) {
    unsigned int u = __float_as_uint(x);
    unsigned int r = (u + 0x7fffu + ((u >> 16) & 1u)) >> 16;
    return (unsigned short)r;
}

// ----------------------------------------------------------------------------
// Setup: P[b,t,n] = intrins[b] @ RT[b,t,n][:3,:]  (3x4)
//        theta[b,t] cumulative affine (3x4): t=2 -> I, t=1 -> M4[b,1],
//        t=0 -> M4[b,0] @ M4[b,1]
// ----------------------------------------------------------------------------
__global__ void setup_kernel(const float* __restrict__ RT,
                             const float* __restrict__ intrins,
                             const float* __restrict__ DoF,
                             float* __restrict__ P,
                             float* __restrict__ theta) {
    int tid = threadIdx.x;
    if (tid < NB * NT * NCAM) {
        int bt = tid / NCAM;
        int b = bt / NT;
        const float* I3 = intrins + b * 9;
        const float* R = RT + (size_t)tid * 16;
        float* Pp = P + tid * 12;
        for (int r = 0; r < 3; ++r)
            for (int c = 0; c < 4; ++c) {
                float s = 0.f;
                for (int k = 0; k < 3; ++k) s += I3[r * 3 + k] * R[k * 4 + c];
                Pp[r * 4 + c] = s;
            }
    }
    if (tid >= 64 && tid < 64 + NB) {
        int b = tid - 64;
        const float* D0 = DoF + (size_t)(b * NT + 0) * 16;
        const float* D1 = DoF + (size_t)(b * NT + 1) * 16;
        float* th = theta + (size_t)b * NT * 12;
        for (int i = 0; i < 12; ++i) th[2 * 12 + i] = 0.f;
        th[2 * 12 + 0] = 1.f; th[2 * 12 + 5] = 1.f; th[2 * 12 + 10] = 1.f;
        for (int i = 0; i < 12; ++i) th[1 * 12 + i] = D1[i];
        for (int r = 0; r < 3; ++r)
            for (int c = 0; c < 4; ++c) {
                float s = (c == 3) ? D0[r * 4 + 3] : 0.f;
                for (int k = 0; k < 3; ++k) s += D0[r * 4 + k] * D1[k * 4 + c];
                th[0 * 12 + r * 4 + c] = s;
            }
    }
}

// ----------------------------------------------------------------------------
// Transpose features (B,T,N,C,FD,FH,FW) fp32 -> [btn][pos][C16] bf16
// reads coalesced per channel, 32B write per thread, fully coalesced
// ----------------------------------------------------------------------------
__global__ __launch_bounds__(256) void transpose_feat_bf16(
    const float* __restrict__ feat, unsigned short* __restrict__ ft) {
    size_t tid = (size_t)blockIdx.x * 256 + threadIdx.x;
    int pos = (int)(tid % FSZ);
    int btn = (int)(tid / FSZ);
    const float* src = feat + (size_t)btn * CAMSZ + pos;
    float v[NC];
#pragma unroll
    for (int c = 0; c < NC; ++c) v[c] = src[(size_t)c * FSZ];
    unsigned int packed[8];
#pragma unroll
    for (int j = 0; j < 8; ++j)
        packed[j] = (unsigned int)f2bf_rne(v[2 * j]) |
                    ((unsigned int)f2bf_rne(v[2 * j + 1]) << 16);
    uint4* dst = reinterpret_cast<uint4*>(ft + ((size_t)btn * FSZ + pos) * NC);
    dst[0] = make_uint4(packed[0], packed[1], packed[2], packed[3]);
    dst[1] = make_uint4(packed[4], packed[5], packed[6], packed[7]);
}

// ----------------------------------------------------------------------------
// Kernel 1 (bf16 path): trilinear sample (6 cams x 16 ch, bf16 chlast feats)
// + W_N matvec (fp32) + ReLU -> h bf16 channel-last [bt][vid][OC]
// vid = gx*GZ*GY + gz*GY + gy (matches reference (gx, gz, gy) order)
// ----------------------------------------------------------------------------
__global__ __launch_bounds__(256) void sample_mlp1_bf16(
    const unsigned short* __restrict__ ft,
    const float* __restrict__ P,
    const float* __restrict__ W_N,
    const float* __restrict__ b_N,
    unsigned short* __restrict__ h) {
    int tid = blockIdx.x * 256 + threadIdx.x;
    int vid = tid % NVOX;
    int bt = tid / NVOX;
    int gy = vid % GY;
    int r2 = vid / GY;
    int gz = r2 % GZ;
    int gx = r2 / GZ;
    float X = (float)gx - 49.5f;
    float Y = (float)gy - 49.5f;
    float Z = (float)gz - 2.5f;

    float acc[OC];
#pragma unroll
    for (int o = 0; o < OC; ++o) acc[o] = b_N[o];

    for (int n = 0; n < NCAM; ++n) {
        const float* Pp = P + (bt * NCAM + n) * 12;
        float px = Pp[0] * X + Pp[1] * Y + Pp[2] * Z + Pp[3];
        float py = Pp[4] * X + Pp[5] * Y + Pp[6] * Z + Pp[7];
        float pz = Pp[8] * X + Pp[9] * Y + Pp[10] * Z + Pp[11];
        float zc = fmaxf(pz, 1e-5f);
        float ix = px / zc;                       // = u (normalization round-trips)
        float iy = py / zc;
        float iz = (pz - 2.0f) * (48.0f / 44.8f); // = dbin
        float x0 = floorf(ix), y0 = floorf(iy), z0 = floorf(iz);
        float wx1 = ix - x0, wy1 = iy - y0, wz1 = iz - z0;
        float wx0 = 1.f - wx1, wy0 = 1.f - wy1, wz0 = 1.f - wz1;

        float w8[8];
        int off8[8];
#pragma unroll
        for (int k = 0; k < 8; ++k) {
            float xf = x0 + (float)(k & 1);
            float yf = y0 + (float)((k >> 1) & 1);
            float zf = z0 + (float)(k >> 2);
            bool valid = (xf >= 0.f) & (xf <= (float)(FW - 1)) &
                         (yf >= 0.f) & (yf <= (float)(FH - 1)) &
                         (zf >= 0.f) & (zf <= (float)(FD - 1));
            int xi = (int)fminf(fmaxf(xf, 0.f), (float)(FW - 1));
            int yi = (int)fminf(fmaxf(yf, 0.f), (float)(FH - 1));
            int zi = (int)fminf(fmaxf(zf, 0.f), (float)(FD - 1));
            float w = ((k & 1) ? wx1 : wx0) * (((k >> 1) & 1) ? wy1 : wy0) *
                      ((k >> 2) ? wz1 : wz0);
            w8[k] = valid ? w : 0.f;
            off8[k] = (zi * FH + yi) * FW + xi;
        }

        float s[NC];
#pragma unroll
        for (int c = 0; c < NC; ++c) s[c] = 0.f;

        const size_t camBase = (size_t)(bt * NCAM + n) * FSZ;
#pragma unroll
        for (int k = 0; k < 8; ++k) {
            float w = w8[k];
            const uint4* cp = reinterpret_cast<const uint4*>(
                ft + (camBase + (size_t)off8[k]) * NC);
            uint4 a = cp[0], b2 = cp[1];
            unsigned int uu[8] = {a.x, a.y, a.z, a.w, b2.x, b2.y, b2.z, b2.w};
#pragma unroll
            for (int j = 0; j < 8; ++j) {
                s[2 * j + 0] = fmaf(w, __uint_as_float(uu[j] << 16), s[2 * j + 0]);
                s[2 * j + 1] = fmaf(w, __uint_as_float(uu[j] & 0xffff0000u), s[2 * j + 1]);
            }
        }

        // acc[o] += W_N[o, n*16 + c] * s[c]  (uniform-address -> s_load)
#pragma unroll
        for (int o = 0; o < OC; ++o) {
            const float4* w4 =
                reinterpret_cast<const float4*>(W_N + o * (NCAM * NC) + n * NC);
#pragma unroll
            for (int q = 0; q < 4; ++q) {
                float4 w = w4[q];
                acc[o] = fmaf(w.x, s[4 * q + 0], acc[o]);
                acc[o] = fmaf(w.y, s[4 * q + 1], acc[o]);
                acc[o] = fmaf(w.z, s[4 * q + 2], acc[o]);
                acc[o] = fmaf(w.w, s[4 * q + 3], acc[o]);
            }
        }
    }

    // pack ReLU(acc) to bf16, store 5x uint4 (80B) channel-last
    unsigned int packed[OC / 2];
#pragma unroll
    for (int j = 0; j < OC / 2; ++j) {
        float a0 = fmaxf(acc[2 * j + 0], 0.f);
        float a1 = fmaxf(acc[2 * j + 1], 0.f);
        packed[j] = (unsigned int)f2bf_rne(a0) | ((unsigned int)f2bf_rne(a1) << 16);
    }
    uint4* hp = reinterpret_cast<uint4*>(h + ((size_t)bt * NVOX + (size_t)vid) * OC);
#pragma unroll
    for (int q = 0; q < 5; ++q)
        hp[q] = make_uint4(packed[4 * q], packed[4 * q + 1],
                           packed[4 * q + 2], packed[4 * q + 3]);
}

// ----------------------------------------------------------------------------
// Kernel 1 fallback (no workspace for transposed feats): original layout fp32,
// scalar gathers; h fp32 channel-last
// ----------------------------------------------------------------------------
__global__ __launch_bounds__(256) void sample_mlp1_fallback(
    const float* __restrict__ feat,
    const float* __restrict__ P,
    const float* __restrict__ W_N,
    const float* __restrict__ b_N,
    float* __restrict__ h) {
    int tid = blockIdx.x * 256 + threadIdx.x;
    int vid = tid % NVOX;
    int bt = tid / NVOX;
    int gy = vid % GY;
    int r2 = vid / GY;
    int gz = r2 % GZ;
    int gx = r2 / GZ;
    float X = (float)gx - 49.5f;
    float Y = (float)gy - 49.5f;
    float Z = (float)gz - 2.5f;

    float acc[OC];
#pragma unroll
    for (int o = 0; o < OC; ++o) acc[o] = b_N[o];

    for (int n = 0; n < NCAM; ++n) {
        const float* Pp = P + (bt * NCAM + n) * 12;
        float px = Pp[0] * X + Pp[1] * Y + Pp[2] * Z + Pp[3];
        float py = Pp[4] * X + Pp[5] * Y + Pp[6] * Z + Pp[7];
        float pz = Pp[8] * X + Pp[9] * Y + Pp[10] * Z + Pp[11];
        float zc = fmaxf(pz, 1e-5f);
        float ix = px / zc;
        float iy = py / zc;
        float iz = (pz - 2.0f) * (48.0f / 44.8f);
        float x0 = floorf(ix), y0 = floorf(iy), z0 = floorf(iz);
        float wx1 = ix - x0, wy1 = iy - y0, wz1 = iz - z0;
        float wx0 = 1.f - wx1, wy0 = 1.f - wy1, wz0 = 1.f - wz1;

        float w8[8];
        int off8[8];
#pragma unroll
        for (int k = 0; k < 8; ++k) {
            float xf = x0 + (float)(k & 1);
            float yf = y0 + (float)((k >> 1) & 1);
            float zf = z0 + (float)(k >> 2);
            bool valid = (xf >= 0.f) & (xf <= (float)(FW - 1)) &
                         (yf >= 0.f) & (yf <= (float)(FH - 1)) &
                         (zf >= 0.f) & (zf <= (float)(FD - 1));
            int xi = (int)fminf(fmaxf(xf, 0.f), (float)(FW - 1));
            int yi = (int)fminf(fmaxf(yf, 0.f), (float)(FH - 1));
            int zi = (int)fminf(fmaxf(zf, 0.f), (float)(FD - 1));
            float w = ((k & 1) ? wx1 : wx0) * (((k >> 1) & 1) ? wy1 : wy0) *
                      ((k >> 2) ? wz1 : wz0);
            w8[k] = valid ? w : 0.f;
            off8[k] = (zi * FH + yi) * FW + xi;
        }

        const float* fn = feat + (size_t)bt * BTSZ + (size_t)n * CAMSZ;
        float s[NC];
#pragma unroll
        for (int c = 0; c < NC; ++c) {
            const float* fc = fn + (size_t)c * FSZ;
            float v = 0.f;
#pragma unroll
            for (int k = 0; k < 8; ++k) v = fmaf(w8[k], fc[off8[k]], v);
            s[c] = v;
        }

#pragma unroll
        for (int o = 0; o < OC; ++o) {
            const float4* w4 =
                reinterpret_cast<const float4*>(W_N + o * (NCAM * NC) + n * NC);
#pragma unroll
            for (int q = 0; q < 4; ++q) {
                float4 w = w4[q];
                acc[o] = fmaf(w.x, s[4 * q + 0], acc[o]);
                acc[o] = fmaf(w.y, s[4 * q + 1], acc[o]);
                acc[o] = fmaf(w.z, s[4 * q + 2], acc[o]);
                acc[o] = fmaf(w.w, s[4 * q + 3], acc[o]);
            }
        }
    }

    float4* hp = reinterpret_cast<float4*>(
        h + ((size_t)bt * NVOX + (size_t)vid) * OC);
#pragma unroll
    for (int q = 0; q < 10; ++q)
        hp[q] = make_float4(fmaxf(acc[4 * q + 0], 0.f), fmaxf(acc[4 * q + 1], 0.f),
                            fmaxf(acc[4 * q + 2], 0.f), fmaxf(acc[4 * q + 3], 0.f));
}

// ----------------------------------------------------------------------------
// Kernel 2: temporal affine warp (trilinear on channel-last h) + W_T + ReLU
// HT = unsigned short (bf16 h) or float (fp32 h). out (B,40,100,8,100) fp32.
// ----------------------------------------------------------------------------
template <typename HT>
__global__ __launch_bounds__(256) void warp_mlp2(
    const HT* __restrict__ h,
    const float* __restrict__ theta,
    const float* __restrict__ W_T,
    const float* __restrict__ b_T,
    float* __restrict__ out) {
    int tid = blockIdx.x * 256 + threadIdx.x;
    int vid = tid % NVOX;
    int b = tid / NVOX;
    int w_ = vid % GY;        // Wp = 100
    int r2 = vid / GY;
    int h_ = r2 % GZ;         // Hp = 8
    int d_ = r2 / GZ;         // Dp = 100

    float xg = -1.f + 2.f * (float)w_ / 99.f;
    float yg = -1.f + 2.f * (float)h_ / 7.f;
    float zg = -1.f + 2.f * (float)d_ / 99.f;

    float acc[OC];
#pragma unroll
    for (int o = 0; o < OC; ++o) acc[o] = b_T[o];

    for (int t = 0; t < NT; ++t) {
        const float* th = theta + (b * NT + t) * 12;
        float g0 = th[0] * xg + th[1] * yg + th[2] * zg + th[3];
        float g1 = th[4] * xg + th[5] * yg + th[6] * zg + th[7];
        float g2 = th[8] * xg + th[9] * yg + th[10] * zg + th[11];
        float ix = (g0 + 1.f) * 0.5f * 99.f;
        float iy = (g1 + 1.f) * 0.5f * 7.f;
        float iz = (g2 + 1.f) * 0.5f * 99.f;
        float x0 = floorf(ix), y0 = floorf(iy), z0 = floorf(iz);
        float wx1 = ix - x0, wy1 = iy - y0, wz1 = iz - z0;
        float wx0 = 1.f - wx1, wy0 = 1.f - wy1, wz0 = 1.f - wz1;

        float w8[8];
        int off8[8];
#pragma unroll
        for (int k = 0; k < 8; ++k) {
            float xf = x0 + (float)(k & 1);
            float yf = y0 + (float)((k >> 1) & 1);
            float zf = z0 + (float)(k >> 2);
            bool valid = (xf >= 0.f) & (xf <= 99.f) &
                         (yf >= 0.f) & (yf <= 7.f) &
                         (zf >= 0.f) & (zf <= 99.f);
            int xi = (int)fminf(fmaxf(xf, 0.f), 99.f);
            int yi = (int)fminf(fmaxf(yf, 0.f), 7.f);
            int zi = (int)fminf(fmaxf(zf, 0.f), 99.f);
            float w = ((k & 1) ? wx1 : wx0) * (((k >> 1) & 1) ? wy1 : wy0) *
                      ((k >> 2) ? wz1 : wz0);
            w8[k] = valid ? w : 0.f;
            off8[k] = (zi * GZ + yi) * GY + xi;
        }

        const HT* hb = h + (size_t)(b * NT + t) * NVOX * OC;
        float sval[OC];
#pragma unroll
        for (int o2 = 0; o2 < OC; ++o2) sval[o2] = 0.f;
#pragma unroll
        for (int k = 0; k < 8; ++k) {
            float w = w8[k];
            if constexpr (sizeof(HT) == 2) {
                const uint4* cp = reinterpret_cast<const uint4*>(
                    (const unsigned short*)hb + (size_t)off8[k] * OC);
#pragma unroll
                for (int q = 0; q < 5; ++q) {
                    uint4 v = cp[q];
                    unsigned int uu[4] = {v.x, v.y, v.z, v.w};
#pragma unroll
                    for (int j = 0; j < 4; ++j) {
                        int c = 8 * q + 2 * j;
                        sval[c + 0] = fmaf(w, __uint_as_float(uu[j] << 16), sval[c + 0]);
                        sval[c + 1] = fmaf(w, __uint_as_float(uu[j] & 0xffff0000u), sval[c + 1]);
                    }
                }
            } else {
                const float4* cp = reinterpret_cast<const float4*>(
                    (const float*)hb + (size_t)off8[k] * OC);
#pragma unroll
                for (int q = 0; q < 10; ++q) {
                    float4 v = cp[q];
                    sval[4 * q + 0] = fmaf(w, v.x, sval[4 * q + 0]);
                    sval[4 * q + 1] = fmaf(w, v.y, sval[4 * q + 1]);
                    sval[4 * q + 2] = fmaf(w, v.z, sval[4 * q + 2]);
                    sval[4 * q + 3] = fmaf(w, v.w, sval[4 * q + 3]);
                }
            }
        }

        // acc[o] += W_T[o, t*40 + o2] * sval[o2]
#pragma unroll
        for (int o = 0; o < OC; ++o) {
            const float4* w4 =
                reinterpret_cast<const float4*>(W_T + o * (NT * OC) + t * OC);
#pragma unroll
            for (int q = 0; q < 10; ++q) {
                float4 w = w4[q];
                acc[o] = fmaf(w.x, sval[4 * q + 0], acc[o]);
                acc[o] = fmaf(w.y, sval[4 * q + 1], acc[o]);
                acc[o] = fmaf(w.z, sval[4 * q + 2], acc[o]);
                acc[o] = fmaf(w.w, sval[4 * q + 3], acc[o]);
            }
        }
    }

    float* op = out + (size_t)b * OC * NVOX + vid;
#pragma unroll
    for (int o = 0; o < OC; ++o) op[(size_t)o * NVOX] = fmaxf(acc[o], 0.f);
}

extern "C" void kernel_launch(void* const* d_in, const int* in_sizes, int n_in,
                              void* d_out, int out_size, void* d_ws, size_t ws_size,
                              hipStream_t stream) {
    const float* frustum = (const float*)d_in[0];
    const float* RT      = (const float*)d_in[1];
    const float* intrins = (const float*)d_in[2];
    const float* DoF     = (const float*)d_in[3];
    const float* W_N     = (const float*)d_in[4];
    const float* b_N     = (const float*)d_in[5];
    const float* W_T     = (const float*)d_in[6];
    const float* b_T     = (const float*)d_in[7];
    float* out = (float*)d_out;

    const size_t ft_bf16 = FT_ELEMS * 2;     // ~85 MB
    const size_t h_bf16  = HSZ * 2;          // ~38 MB
    const size_t h_f32   = HSZ * 4;          // ~77 MB
    const size_t small   = 4096;

    char* base = (char*)d_ws;
    const int tr_blocks = (NB * NT * NCAM * FSZ) / 256;  // 10368
    const int n1_blocks = (NB * NT * NVOX) / 256;        // 1875
    const int n2_blocks = (NB * NVOX) / 256;             // 625

    if (ws_size >= ft_bf16 + h_bf16 + small) {
        // bf16 fast path
        size_t ft_al = (ft_bf16 + 255) & ~(size_t)255;
        unsigned short* ft_buf = (unsigned short*)base;
        unsigned short* h_buf = (unsigned short*)(base + ft_al);
        float* P_buf = (float*)(base + ft_al + ((h_bf16 + 255) & ~(size_t)255));
        float* th_buf = P_buf + NB * NT * NCAM * 12;

        setup_kernel<<<1, 128, 0, stream>>>(RT, intrins, DoF, P_buf, th_buf);
        transpose_feat_bf16<<<tr_blocks, 256, 0, stream>>>(frustum, ft_buf);
        sample_mlp1_bf16<<<n1_blocks, 256, 0, stream>>>(ft_buf, P_buf, W_N, b_N, h_buf);
        warp_mlp2<unsigned short><<<n2_blocks, 256, 0, stream>>>(
            h_buf, th_buf, W_T, b_T, out);
    } else {
        // fallback: no feature transpose, fp32 h
        float* h_buf = (float*)base;
        float* P_buf = (float*)(base + ((h_f32 + 255) & ~(size_t)255));
        float* th_buf = P_buf + NB * NT * NCAM * 12;

        setup_kernel<<<1, 128, 0, stream>>>(RT, intrins, DoF, P_buf, th_buf);
        sample_mlp1_fallback<<<n1_blocks, 256, 0, stream>>>(
            frustum, P_buf, W_N, b_N, h_buf);
        warp_mlp2<float><<<n2_blocks, 256, 0, stream>>>(
            h_buf, th_buf, W_T, b_T, out);
    }
}

// Round 4
// 562.951 us; speedup vs baseline: 1.1693x; 1.1693x over previous
//
#include <hip/hip_runtime.h>

// ---- problem constants (from reference) ----
#define NB 2
#define NT 3
#define NCAM 6
#define NC 16
#define FD 48
#define FH 24
#define FW 64
#define GX 100
#define GY 100
#define GZ 8
#define OC 40
#define NVOX (GX * GY * GZ)          // 80000
#define FSZ (FD * FH * FW)           // 73728 voxels per channel volume
#define CAMSZ (NC * FSZ)             // per-camera feature volume (orig layout)
#define BTSZ (NCAM * CAMSZ)          // per-(b,t) feature block (orig layout)
#define HSZ ((size_t)NB * NT * OC * NVOX)             // 19,200,000 elems
#define FT_ELEMS ((size_t)NB * NT * NCAM * FSZ * NC)  // 42,467,328 elems

// ----------------------------------------------------------------------------
// Setup: P[b,t,n] = intrins[b] @ RT[b,t,n][:3,:]  (3x4)
//        theta[b,t] cumulative affine (3x4): t=2 -> I, t=1 -> M4[b,1],
//        t=0 -> M4[b,0] @ M4[b,1]
// ----------------------------------------------------------------------------
__global__ void setup_kernel(const float* __restrict__ RT,
                             const float* __restrict__ intrins,
                             const float* __restrict__ DoF,
                             float* __restrict__ P,
                             float* __restrict__ theta) {
    int tid = threadIdx.x;
    if (tid < NB * NT * NCAM) {
        int bt = tid / NCAM;
        int b = bt / NT;
        const float* I3 = intrins + b * 9;
        const float* R = RT + (size_t)tid * 16;
        float* Pp = P + tid * 12;
        for (int r = 0; r < 3; ++r)
            for (int c = 0; c < 4; ++c) {
                float s = 0.f;
                for (int k = 0; k < 3; ++k) s += I3[r * 3 + k] * R[k * 4 + c];
                Pp[r * 4 + c] = s;
            }
    }
    if (tid >= 64 && tid < 64 + NB) {
        int b = tid - 64;
        const float* D0 = DoF + (size_t)(b * NT + 0) * 16;
        const float* D1 = DoF + (size_t)(b * NT + 1) * 16;
        float* th = theta + (size_t)b * NT * 12;
        for (int i = 0; i < 12; ++i) th[2 * 12 + i] = 0.f;
        th[2 * 12 + 0] = 1.f; th[2 * 12 + 5] = 1.f; th[2 * 12 + 10] = 1.f;
        for (int i = 0; i < 12; ++i) th[1 * 12 + i] = D1[i];
        for (int r = 0; r < 3; ++r)
            for (int c = 0; c < 4; ++c) {
                float s = (c == 3) ? D0[r * 4 + 3] : 0.f;
                for (int k = 0; k < 3; ++k) s += D0[r * 4 + k] * D1[k * 4 + c];
                th[0 * 12 + r * 4 + c] = s;
            }
    }
}

// ----------------------------------------------------------------------------
// Transpose features (B,T,N,C,FD,FH,FW) fp32 -> [btn][pos][C16] fp32 chlast
// ----------------------------------------------------------------------------
__global__ __launch_bounds__(256) void transpose_feat_f32(
    const float* __restrict__ feat, float* __restrict__ ft) {
    size_t tid = (size_t)blockIdx.x * 256 + threadIdx.x;
    int pos = (int)(tid % FSZ);
    int btn = (int)(tid / FSZ);
    const float* src = feat + (size_t)btn * CAMSZ + pos;
    float v[NC];
#pragma unroll
    for (int c = 0; c < NC; ++c) v[c] = src[(size_t)c * FSZ];
    float4* dst = reinterpret_cast<float4*>(ft + ((size_t)btn * FSZ + pos) * NC);
#pragma unroll
    for (int q = 0; q < 4; ++q)
        dst[q] = make_float4(v[4 * q], v[4 * q + 1], v[4 * q + 2], v[4 * q + 3]);
}

// ----------------------------------------------------------------------------
// Kernel 1: trilinear sample (6 cams x 16 ch, fp32 chlast feats) with per-cam
// frustum culling + W_N matvec + ReLU -> h fp32 channel-last [bt][vid][OC]
// Culling is exact: skipped cams have all 8 corner weights == 0.
// ----------------------------------------------------------------------------
template <bool CHLAST>
__global__ __launch_bounds__(256) void sample_mlp1_f32(
    const float* __restrict__ feat,   // original layout (when !CHLAST)
    const float* __restrict__ ft,     // channel-last (when CHLAST)
    const float* __restrict__ P,
    const float* __restrict__ W_N,
    const float* __restrict__ b_N,
    float* __restrict__ h) {
    int tid = blockIdx.x * 256 + threadIdx.x;
    int vid = tid % NVOX;
    int bt = tid / NVOX;
    int gy = vid % GY;
    int r2 = vid / GY;
    int gz = r2 % GZ;
    int gx = r2 / GZ;
    float X = (float)gx - 49.5f;
    float Y = (float)gy - 49.5f;
    float Z = (float)gz - 2.5f;

    float acc[OC];
#pragma unroll
    for (int o = 0; o < OC; ++o) acc[o] = b_N[o];

    for (int n = 0; n < NCAM; ++n) {
        const float* Pp = P + (bt * NCAM + n) * 12;
        float px = Pp[0] * X + Pp[1] * Y + Pp[2] * Z + Pp[3];
        float py = Pp[4] * X + Pp[5] * Y + Pp[6] * Z + Pp[7];
        float pz = Pp[8] * X + Pp[9] * Y + Pp[10] * Z + Pp[11];
        float zc = fmaxf(pz, 1e-5f);
        float ix = px / zc;                       // = u (normalization round-trips)
        float iy = py / zc;
        float iz = (pz - 2.0f) * (48.0f / 44.8f); // = dbin
        float x0 = floorf(ix), y0 = floorf(iy), z0 = floorf(iz);

        // frustum cull: all 8 corners out-of-bounds -> contribution exactly 0
        if (x0 < -1.f || x0 > (float)(FW - 1) ||
            y0 < -1.f || y0 > (float)(FH - 1) ||
            z0 < -1.f || z0 > (float)(FD - 1)) continue;

        float wx1 = ix - x0, wy1 = iy - y0, wz1 = iz - z0;
        float wx0 = 1.f - wx1, wy0 = 1.f - wy1, wz0 = 1.f - wz1;

        float w8[8];
        int off8[8];
#pragma unroll
        for (int k = 0; k < 8; ++k) {
            float xf = x0 + (float)(k & 1);
            float yf = y0 + (float)((k >> 1) & 1);
            float zf = z0 + (float)(k >> 2);
            bool valid = (xf >= 0.f) & (xf <= (float)(FW - 1)) &
                         (yf >= 0.f) & (yf <= (float)(FH - 1)) &
                         (zf >= 0.f) & (zf <= (float)(FD - 1));
            int xi = (int)fminf(fmaxf(xf, 0.f), (float)(FW - 1));
            int yi = (int)fminf(fmaxf(yf, 0.f), (float)(FH - 1));
            int zi = (int)fminf(fmaxf(zf, 0.f), (float)(FD - 1));
            float w = ((k & 1) ? wx1 : wx0) * (((k >> 1) & 1) ? wy1 : wy0) *
                      ((k >> 2) ? wz1 : wz0);
            w8[k] = valid ? w : 0.f;
            off8[k] = (zi * FH + yi) * FW + xi;
        }

        float s[NC];
#pragma unroll
        for (int c = 0; c < NC; ++c) s[c] = 0.f;

        if constexpr (CHLAST) {
            const size_t camBase = (size_t)(bt * NCAM + n) * FSZ;
#pragma unroll
            for (int k = 0; k < 8; ++k) {
                float w = w8[k];
                const float4* cp = reinterpret_cast<const float4*>(
                    ft + (camBase + (size_t)off8[k]) * NC);
#pragma unroll
                for (int q = 0; q < 4; ++q) {
                    float4 v = cp[q];
                    s[4 * q + 0] = fmaf(w, v.x, s[4 * q + 0]);
                    s[4 * q + 1] = fmaf(w, v.y, s[4 * q + 1]);
                    s[4 * q + 2] = fmaf(w, v.z, s[4 * q + 2]);
                    s[4 * q + 3] = fmaf(w, v.w, s[4 * q + 3]);
                }
            }
        } else {
            const float* fn = feat + (size_t)bt * BTSZ + (size_t)n * CAMSZ;
#pragma unroll
            for (int c = 0; c < NC; ++c) {
                const float* fc = fn + (size_t)c * FSZ;
                float v = 0.f;
#pragma unroll
                for (int k = 0; k < 8; ++k) v = fmaf(w8[k], fc[off8[k]], v);
                s[c] = v;
            }
        }

        // acc[o] += W_N[o, n*16 + c] * s[c]
#pragma unroll
        for (int o = 0; o < OC; ++o) {
            const float4* w4 =
                reinterpret_cast<const float4*>(W_N + o * (NCAM * NC) + n * NC);
#pragma unroll
            for (int q = 0; q < 4; ++q) {
                float4 w = w4[q];
                acc[o] = fmaf(w.x, s[4 * q + 0], acc[o]);
                acc[o] = fmaf(w.y, s[4 * q + 1], acc[o]);
                acc[o] = fmaf(w.z, s[4 * q + 2], acc[o]);
                acc[o] = fmaf(w.w, s[4 * q + 3], acc[o]);
            }
        }
    }

    float4* hp = reinterpret_cast<float4*>(
        h + ((size_t)bt * NVOX + (size_t)vid) * OC);
#pragma unroll
    for (int q = 0; q < 10; ++q)
        hp[q] = make_float4(fmaxf(acc[4 * q + 0], 0.f), fmaxf(acc[4 * q + 1], 0.f),
                            fmaxf(acc[4 * q + 2], 0.f), fmaxf(acc[4 * q + 3], 0.f));
}

// ----------------------------------------------------------------------------
// Kernel 2 (t-split): one thread per (b, voxel, t). Block = 192 threads =
// 64 consecutive voxels x 3 waves (wave w <-> t=w, uniform per wave).
// Each thread gathers sval[40] for its t, computes partial W_T dot-products,
// LDS-atomic-accumulates into red[64][41], then bias+ReLU+coalesced store.
// grid = NB * NVOX/64 = 2500 blocks -> 7500 waves (~29/CU available)
// ----------------------------------------------------------------------------
__global__ __launch_bounds__(192) void warp_mlp2_tsplit(
    const float* __restrict__ h,
    const float* __restrict__ theta,
    const float* __restrict__ W_T,
    const float* __restrict__ b_T,
    float* __restrict__ out) {
    __shared__ float red[64][41];   // padded: conflict-free atomics
    int tid = threadIdx.x;
    int t = tid >> 6;               // wave index = temporal index
    int v = tid & 63;
    int blk = blockIdx.x;
    int b = blk / (NVOX / 64);      // 1250 voxel-blocks per batch
    int vb = blk % (NVOX / 64);
    int vid = vb * 64 + v;
    int w_ = vid % GY;              // Wp = 100
    int r2 = vid / GY;
    int h_ = r2 % GZ;               // Hp = 8
    int d_ = r2 / GZ;               // Dp = 100

    for (int i = tid; i < 64 * 41; i += 192) (&red[0][0])[i] = 0.f;
    __syncthreads();

    float xg = -1.f + 2.f * (float)w_ / 99.f;
    float yg = -1.f + 2.f * (float)h_ / 7.f;
    float zg = -1.f + 2.f * (float)d_ / 99.f;

    const float* th = theta + (b * NT + t) * 12;
    float g0 = th[0] * xg + th[1] * yg + th[2] * zg + th[3];
    float g1 = th[4] * xg + th[5] * yg + th[6] * zg + th[7];
    float g2 = th[8] * xg + th[9] * yg + th[10] * zg + th[11];
    float ix = (g0 + 1.f) * 0.5f * 99.f;
    float iy = (g1 + 1.f) * 0.5f * 7.f;
    float iz = (g2 + 1.f) * 0.5f * 99.f;
    float x0 = floorf(ix), y0 = floorf(iy), z0 = floorf(iz);
    float wx1 = ix - x0, wy1 = iy - y0, wz1 = iz - z0;
    float wx0 = 1.f - wx1, wy0 = 1.f - wy1, wz0 = 1.f - wz1;

    float w8[8];
    int off8[8];
#pragma unroll
    for (int k = 0; k < 8; ++k) {
        float xf = x0 + (float)(k & 1);
        float yf = y0 + (float)((k >> 1) & 1);
        float zf = z0 + (float)(k >> 2);
        bool valid = (xf >= 0.f) & (xf <= 99.f) &
                     (yf >= 0.f) & (yf <= 7.f) &
                     (zf >= 0.f) & (zf <= 99.f);
        int xi = (int)fminf(fmaxf(xf, 0.f), 99.f);
        int yi = (int)fminf(fmaxf(yf, 0.f), 7.f);
        int zi = (int)fminf(fmaxf(zf, 0.f), 99.f);
        float w = ((k & 1) ? wx1 : wx0) * (((k >> 1) & 1) ? wy1 : wy0) *
                  ((k >> 2) ? wz1 : wz0);
        w8[k] = valid ? w : 0.f;
        off8[k] = (zi * GZ + yi) * GY + xi;
    }

    const float* hb = h + (size_t)(b * NT + t) * NVOX * OC;
    float sval[OC];
#pragma unroll
    for (int o2 = 0; o2 < OC; ++o2) sval[o2] = 0.f;
#pragma unroll
    for (int k = 0; k < 8; ++k) {
        float w = w8[k];
        const float4* cp =
            reinterpret_cast<const float4*>(hb + (size_t)off8[k] * OC);
#pragma unroll
        for (int q = 0; q < 10; ++q) {
            float4 vv = cp[q];
            sval[4 * q + 0] = fmaf(w, vv.x, sval[4 * q + 0]);
            sval[4 * q + 1] = fmaf(w, vv.y, sval[4 * q + 1]);
            sval[4 * q + 2] = fmaf(w, vv.z, sval[4 * q + 2]);
            sval[4 * q + 3] = fmaf(w, vv.w, sval[4 * q + 3]);
        }
    }

    // partial[o] = sum_o2 W_T[o, t*40 + o2] * sval[o2]; 4 outputs at a time
#pragma unroll
    for (int o = 0; o < OC; o += 4) {
        float p0 = 0.f, p1 = 0.f, p2 = 0.f, p3 = 0.f;
        const float4* w0 = reinterpret_cast<const float4*>(
            W_T + (o + 0) * (NT * OC) + t * OC);
        const float4* w1 = reinterpret_cast<const float4*>(
            W_T + (o + 1) * (NT * OC) + t * OC);
        const float4* w2 = reinterpret_cast<const float4*>(
            W_T + (o + 2) * (NT * OC) + t * OC);
        const float4* w3 = reinterpret_cast<const float4*>(
            W_T + (o + 3) * (NT * OC) + t * OC);
#pragma unroll
        for (int q = 0; q < 10; ++q) {
            float4 a0 = w0[q], a1 = w1[q], a2 = w2[q], a3 = w3[q];
            float s0 = sval[4 * q + 0], s1 = sval[4 * q + 1];
            float s2 = sval[4 * q + 2], s3 = sval[4 * q + 3];
            p0 = fmaf(a0.x, s0, p0); p0 = fmaf(a0.y, s1, p0);
            p0 = fmaf(a0.z, s2, p0); p0 = fmaf(a0.w, s3, p0);
            p1 = fmaf(a1.x, s0, p1); p1 = fmaf(a1.y, s1, p1);
            p1 = fmaf(a1.z, s2, p1); p1 = fmaf(a1.w, s3, p1);
            p2 = fmaf(a2.x, s0, p2); p2 = fmaf(a2.y, s1, p2);
            p2 = fmaf(a2.z, s2, p2); p2 = fmaf(a2.w, s3, p2);
            p3 = fmaf(a3.x, s0, p3); p3 = fmaf(a3.y, s1, p3);
            p3 = fmaf(a3.z, s2, p3); p3 = fmaf(a3.w, s3, p3);
        }
        atomicAdd(&red[v][o + 0], p0);
        atomicAdd(&red[v][o + 1], p1);
        atomicAdd(&red[v][o + 2], p2);
        atomicAdd(&red[v][o + 3], p3);
    }
    __syncthreads();

    // write out: 64 voxels x 40 outputs; coalesced rows of 64
    for (int idx = tid; idx < 64 * OC; idx += 192) {
        int o = idx >> 6;
        int vv = idx & 63;
        float val = red[vv][o] + b_T[o];
        out[((size_t)b * OC + o) * NVOX + (size_t)vb * 64 + vv] = fmaxf(val, 0.f);
    }
}

extern "C" void kernel_launch(void* const* d_in, const int* in_sizes, int n_in,
                              void* d_out, int out_size, void* d_ws, size_t ws_size,
                              hipStream_t stream) {
    const float* frustum = (const float*)d_in[0];
    const float* RT      = (const float*)d_in[1];
    const float* intrins = (const float*)d_in[2];
    const float* DoF     = (const float*)d_in[3];
    const float* W_N     = (const float*)d_in[4];
    const float* b_N     = (const float*)d_in[5];
    const float* W_T     = (const float*)d_in[6];
    const float* b_T     = (const float*)d_in[7];
    float* out = (float*)d_out;

    const size_t ft_f32 = FT_ELEMS * sizeof(float);   // ~170 MB
    const size_t h_f32  = HSZ * sizeof(float);        // ~77 MB
    const size_t small  = 4096;

    char* base = (char*)d_ws;
    const int tr_blocks = (NB * NT * NCAM * FSZ) / 256;  // 10368
    const int n1_blocks = (NB * NT * NVOX) / 256;        // 1875
    const int n2_blocks = NB * (NVOX / 64);              // 2500

    if (ws_size >= ft_f32 + h_f32 + small) {
        // fast path: fp32 channel-last features
        size_t ft_al = (ft_f32 + 255) & ~(size_t)255;
        float* ft_buf = (float*)base;
        float* h_buf = (float*)(base + ft_al);
        float* P_buf = (float*)(base + ft_al + ((h_f32 + 255) & ~(size_t)255));
        float* th_buf = P_buf + NB * NT * NCAM * 12;

        setup_kernel<<<1, 128, 0, stream>>>(RT, intrins, DoF, P_buf, th_buf);
        transpose_feat_f32<<<tr_blocks, 256, 0, stream>>>(frustum, ft_buf);
        sample_mlp1_f32<true><<<n1_blocks, 256, 0, stream>>>(
            nullptr, ft_buf, P_buf, W_N, b_N, h_buf);
        warp_mlp2_tsplit<<<n2_blocks, 192, 0, stream>>>(
            h_buf, th_buf, W_T, b_T, out);
    } else {
        // fallback: no feature transpose (original layout gathers), fp32 h
        float* h_buf = (float*)base;
        float* P_buf = (float*)(base + ((h_f32 + 255) & ~(size_t)255));
        float* th_buf = P_buf + NB * NT * NCAM * 12;

        setup_kernel<<<1, 128, 0, stream>>>(RT, intrins, DoF, P_buf, th_buf);
        sample_mlp1_f32<false><<<n1_blocks, 256, 0, stream>>>(
            frustum, nullptr, P_buf, W_N, b_N, h_buf);
        warp_mlp2_tsplit<<<n2_blocks, 192, 0, stream>>>(
            h_buf, th_buf, W_T, b_T, out);
    }
}